// Round 8
// baseline (120.095 us; speedup 1.0000x reference)
//
#include <hip/hip_runtime.h>
#include <math.h>

#define PROJ 8192
#define NB   16
#define NC   512
#define HW   196      // 14*14
#define KP   224      // K padded (7 chunks of 32)
#define NROW (NB * NC)          // 8192 rows
#define XELE ((size_t)NROW * KP)  // elems per bf16 array = 1,835,008

typedef __attribute__((ext_vector_type(8))) short bf16x8;   // MFMA A/B frag
typedef __attribute__((ext_vector_type(4))) short short4v;
typedef __attribute__((ext_vector_type(4))) float f32x4;    // MFMA C/D frag

__device__ __forceinline__ unsigned bf16_rne(float f) {
    unsigned u = __builtin_bit_cast(unsigned, f);
    return (u + 0x7fffu + ((u >> 16) & 1u)) >> 16;
}

// ---------------------------------------------------------------------------
// Kernel 0 (prep): x fp32 [8192 rows x 196] -> xh/xl bf16 [8192 x 224],
// zero-padded K. Split precision: x = hi + lo (lo*lo dropped later, ~2^-18).
// grid = 8192*56/256 = 1792 blocks.
// ---------------------------------------------------------------------------
__global__ __launch_bounds__(256)
void cbp_prep(const float* __restrict__ x,
              short* __restrict__ xh, short* __restrict__ xl) {
    const int id  = blockIdx.x * 256 + threadIdx.x;   // quad id over 8192*56
    const int q   = id % 56;                          // k-quad 0..55
    const int row = id / 56;
    float4 v = {0.f, 0.f, 0.f, 0.f};
    if (q < 49) v = *(const float4*)&x[(size_t)row * HW + 4 * q];  // 196 = 49*4
    const float f[4] = {v.x, v.y, v.z, v.w};
    short4v h, l;
#pragma unroll
    for (int c = 0; c < 4; ++c) {
        const unsigned hb = bf16_rne(f[c]);
        h[c] = (short)hb;
        l[c] = (short)bf16_rne(f[c] - __builtin_bit_cast(float, hb << 16));
    }
    *(short4v*)&xh[(size_t)row * KP + 4 * q] = h;
    *(short4v*)&xl[(size_t)row * KP + 4 * q] = l;
}

// ---------------------------------------------------------------------------
// Kernel 1 (gram): symmetric 64x64 tiles, upper triangle only (36/batch).
// grid = 576 blocks x 256 threads (4 waves, each a 32x32 sub-tile).
// blk -> xcd = blk&7 pins a batch pair: b = 2*xcd + (idx>=36), idx = blk>>3.
// Fragments loaded DIRECTLY from global xh/xl (L2-resident) — no LDS staging,
// no syncthreads in the K-loop. LDS = 32KB private sketch + signs/hashes.
// Off-diagonal tiles scatter both orientations (G symmetric).
// ---------------------------------------------------------------------------
#define LOADFRAGS(buf, kc)                                             \
    {                                                                  \
        _Pragma("unroll")                                              \
        for (int i = 0; i < 2; ++i) {                                  \
            ah[buf][i] = *(const bf16x8*)&pAh[i * 3584 + (kc) * 32];   \
            al[buf][i] = *(const bf16x8*)&pAl[i * 3584 + (kc) * 32];   \
            bh[buf][i] = *(const bf16x8*)&pBh[i * 3584 + (kc) * 32];   \
            bl[buf][i] = *(const bf16x8*)&pBl[i * 3584 + (kc) * 32];   \
        }                                                              \
    }

__global__ __launch_bounds__(256, 4)
void cbp_gram(const short* __restrict__ xh, const short* __restrict__ xl,
              const float* __restrict__ s1, const float* __restrict__ s2,
              const int*   __restrict__ h1, const int*   __restrict__ h2,
              float* __restrict__ partials) {
    __shared__ float sk[PROJ];                 // 32 KB private sketch
    __shared__ int   rh1[64], rh2[64], ch1[64], ch2[64];
    __shared__ float rs1[64], rs2[64], cs1[64], cs2[64];

    const int tid = threadIdx.x;
    const int blk = blockIdx.x;
    const int xcd = blk & 7;
    const int idx = blk >> 3;                  // 0..71
    const int hi  = (idx >= 36) ? 1 : 0;
    const int b   = 2 * xcd + hi;
    int I = 0, uu = idx - 36 * hi;
    while (uu >= 8 - I) { uu -= 8 - I; ++I; }  // upper-tri decode (block-uniform)
    const int J = I + uu;
    const int c1base = I * 64, c2base = J * 64;

    for (int i = tid; i < PROJ; i += 256) sk[i] = 0.f;
    if (tid < 64) {
        rh1[tid] = h1[c1base + tid]; rh2[tid] = h2[c1base + tid];
        rs1[tid] = s1[c1base + tid]; rs2[tid] = s2[c1base + tid];
    } else if (tid < 128) {
        const int t = tid - 64;
        ch1[t] = h1[c2base + t]; ch2[t] = h2[c2base + t];
        cs1[t] = s1[c2base + t]; cs2[t] = s2[c2base + t];
    }
    __syncthreads();

    const int lane = tid & 63, wave = tid >> 6;
    const int quad = lane >> 4, l15 = lane & 15;
    const int wr = (wave >> 1) * 32, wc = (wave & 1) * 32;

    const size_t rowA = ((size_t)b * NC + c1base + wr + l15) * KP + quad * 8;
    const size_t rowB = ((size_t)b * NC + c2base + wc + l15) * KP + quad * 8;
    const short* pAh = xh + rowA;  const short* pAl = xl + rowA;
    const short* pBh = xh + rowB;  const short* pBl = xl + rowB;

    f32x4 acc[2][2];
#pragma unroll
    for (int i = 0; i < 2; ++i)
#pragma unroll
        for (int j = 0; j < 2; ++j) acc[i][j] = (f32x4){0.f, 0.f, 0.f, 0.f};

    bf16x8 ah[2][2], al[2][2], bh[2][2], bl[2][2];   // [buf][i]
    LOADFRAGS(0, 0)
#pragma unroll
    for (int kc = 0; kc < 7; ++kc) {
        const int cur = kc & 1;
        if (kc < 6) LOADFRAGS(cur ^ 1, kc + 1)
#pragma unroll
        for (int i = 0; i < 2; ++i)
#pragma unroll
            for (int j = 0; j < 2; ++j) {
                acc[i][j] = __builtin_amdgcn_mfma_f32_16x16x32_bf16(ah[cur][i], bh[cur][j], acc[i][j], 0, 0, 0);
                acc[i][j] = __builtin_amdgcn_mfma_f32_16x16x32_bf16(ah[cur][i], bl[cur][j], acc[i][j], 0, 0, 0);
                acc[i][j] = __builtin_amdgcn_mfma_f32_16x16x32_bf16(al[cur][i], bh[cur][j], acc[i][j], 0, 0, 0);
            }
    }

    // Scatter. C/D layout: col = lane&15 (c2), row = quad*4+reg (c1).
    const bool offd = (I != J);
#pragma unroll
    for (int i = 0; i < 2; ++i) {
        const int r0 = wr + i * 16 + quad * 4;
#pragma unroll
        for (int j = 0; j < 2; ++j) {
            const int c = wc + j * 16 + l15;
            const int ch2v = ch2[c], ch1v = ch1[c];
            const float cs2v = cs2[c], cs1v = cs1[c];
#pragma unroll
            for (int rg = 0; rg < 4; ++rg) {
                const int r = r0 + rg;
                const float g = acc[i][j][rg];
                atomicAdd(&sk[(rh1[r] + ch2v) & (PROJ - 1)], rs1[r] * cs2v * g);
                if (offd)
                    atomicAdd(&sk[(ch1v + rh2[r]) & (PROJ - 1)], cs1v * rs2[r] * g);
            }
        }
    }
    __syncthreads();

    float4* dst = (float4*)(partials + (size_t)blk * PROJ);
    const float4* src = (const float4*)sk;
    for (int i = tid; i < PROJ / 4; i += 256) dst[i] = src[i];
}

// ---------------------------------------------------------------------------
// Kernel 2 (reduce): sum 36 partials/bin + signed sqrt + per-block ssq.
// grid = 512; blk&7 matches gram's XCD pinning so partial reads hit local L2.
// ---------------------------------------------------------------------------
__global__ __launch_bounds__(256)
void cbp_reduce(const float* __restrict__ partials, float* __restrict__ y,
                float* __restrict__ ssqp) {
    const int blk = blockIdx.x;
    const int xcd = blk & 7;
    const int k   = blk >> 3;          // 0..63
    const int hi  = k >> 5;
    const int seg = k & 31;
    const int b   = 2 * xcd + hi;
    const int tid = threadIdx.x;
    const int bin = seg * 256 + tid;

    float s = 0.f;
#pragma unroll
    for (int u = 0; u < 36; ++u) {
        int u2 = u + seg; if (u2 >= 36) u2 -= 36;      // rotate: spread channels
        const int pb = ((hi * 36 + u2) << 3) | xcd;
        s += partials[(size_t)pb * PROJ + bin];
    }

    const float m = sqrtf(fabsf(s) + 1e-8f);
    const float o = (s > 0.f) ? m : (s < 0.f ? -m : 0.f);   // sign(0)=0
    y[b * PROJ + bin] = o;

    __shared__ float red[256];
    red[tid] = o * o;
    __syncthreads();
#pragma unroll
    for (int st = 128; st >= 1; st >>= 1) {
        if (tid < st) red[tid] += red[tid + st];
        __syncthreads();
    }
    if (tid == 0) ssqp[blk] = red[0];
}

// ---------------------------------------------------------------------------
// Kernel 3 (norm): y_b /= max(||y_b||, 1e-12). grid = 32 (b, half-row).
// ---------------------------------------------------------------------------
__global__ __launch_bounds__(256)
void cbp_normalize(float* __restrict__ y, const float* __restrict__ ssqp) {
    const int b   = blockIdx.x >> 1;
    const int off = (blockIdx.x & 1) * 4096;
    const int tid = threadIdx.x;
    float ssq = 0.f;
#pragma unroll
    for (int seg = 0; seg < 32; ++seg)
        ssq += ssqp[(((b & 1) * 32 + seg) << 3) | (b >> 1)];
    const float inv = 1.0f / fmaxf(sqrtf(ssq), 1e-12f);

    float4* row = (float4*)&y[(size_t)b * PROJ + off];
#pragma unroll
    for (int j = 0; j < 4; ++j) {
        float4 v = row[j * 256 + tid];
        v.x *= inv; v.y *= inv; v.z *= inv; v.w *= inv;
        row[j * 256 + tid] = v;
    }
}

// ---------------------------------------------------------------------------
extern "C" void kernel_launch(void* const* d_in, const int* in_sizes, int n_in,
                              void* d_out, int out_size, void* d_ws, size_t ws_size,
                              hipStream_t stream) {
    const float* x  = (const float*)d_in[0];
    const float* s1 = (const float*)d_in[1];
    const float* s2 = (const float*)d_in[2];
    const int*   h1 = (const int*)d_in[3];
    const int*   h2 = (const int*)d_in[4];
    float* y = (float*)d_out;                    // [16, 8192]

    // ws layout (ws_size = 256 MiB; we use ~26.2 MB):
    short* xh = (short*)d_ws;                    // 3.67 MB
    short* xl = xh + XELE;                       // 3.67 MB
    float* partials = (float*)(xl + XELE);       // 576 * 32 KB = 18.87 MB
    float* ssqp = partials + (size_t)576 * PROJ; // 512 floats

    hipLaunchKernelGGL(cbp_prep, dim3(1792), dim3(256), 0, stream, x, xh, xl);
    hipLaunchKernelGGL(cbp_gram, dim3(576), dim3(256), 0, stream,
                       xh, xl, s1, s2, h1, h2, partials);
    hipLaunchKernelGGL(cbp_reduce, dim3(512), dim3(256), 0, stream,
                       partials, y, ssqp);
    hipLaunchKernelGGL(cbp_normalize, dim3(32), dim3(256), 0, stream, y, ssqp);
}

// Round 9
// 108.235 us; speedup vs baseline: 1.1096x; 1.1096x over previous
//
#include <hip/hip_runtime.h>
#include <math.h>

#define PROJ 8192
#define NB   16
#define NC   512
#define HW   196      // 14*14
#define KP   224      // K padded (7 chunks of 32)
#define XELE ((size_t)NB * NC * KP)   // elems per bf16 array

typedef __attribute__((ext_vector_type(8))) short bf16x8;   // MFMA A/B frag
typedef __attribute__((ext_vector_type(4))) short short4v;
typedef __attribute__((ext_vector_type(4))) float f32x4;    // MFMA C/D frag

__device__ __forceinline__ unsigned bf16_rne(float f) {
    unsigned u = __builtin_bit_cast(unsigned, f);
    return (u + 0x7fffu + ((u >> 16) & 1u)) >> 16;
}

// ---------------------------------------------------------------------------
// Kernel 0 (prep): x fp32 [8192 x 196] -> xh/xl bf16 [8192 x 224] (K padded).
// Split precision: x = hi + lo; G = hh + hl + lh (lo*lo dropped, ~2^-18).
// ---------------------------------------------------------------------------
__global__ __launch_bounds__(256)
void cbp_prep(const float* __restrict__ x,
              short* __restrict__ xh, short* __restrict__ xl) {
    const int id  = blockIdx.x * 256 + threadIdx.x;   // quad id over 8192*56
    const int q   = id % 56;
    const int row = id / 56;
    float4 v = {0.f, 0.f, 0.f, 0.f};
    if (q < 49) v = *(const float4*)&x[(size_t)row * HW + 4 * q];  // 196 = 49*4
    const float f[4] = {v.x, v.y, v.z, v.w};
    short4v h, l;
#pragma unroll
    for (int c = 0; c < 4; ++c) {
        const unsigned hb = bf16_rne(f[c]);
        h[c] = (short)hb;
        l[c] = (short)bf16_rne(f[c] - __builtin_bit_cast(float, hb << 16));
    }
    *(short4v*)&xh[(size_t)row * KP + 4 * q] = h;
    *(short4v*)&xl[(size_t)row * KP + 4 * q] = l;
}

// ---------------------------------------------------------------------------
// Kernel 1 (gram): 256 blocks x 1024 threads (16 waves/CU, 1 block/CU).
// Block = (batch b, quarter q): its 16 waves independently cover 4 full
// 64x64 tiles (4 waves per tile, one 32x32 quadrant each) — no syncthreads
// between sketch-zero and scatter. Frags loaded directly from global xh/xl,
// double-buffered. One private 32KB LDS sketch per block -> partials minimal.
// blk&7 pins an XCD to a batch pair for L2 locality.
// ---------------------------------------------------------------------------
#define LOADFRAGS(buf, kc)                                          \
    {                                                               \
        const int off_ = (kc) * 32;                                 \
        ah[buf][0] = *(const bf16x8*)&pAh[off_];                    \
        ah[buf][1] = *(const bf16x8*)&pAh[16 * KP + off_];          \
        al[buf][0] = *(const bf16x8*)&pAl[off_];                    \
        al[buf][1] = *(const bf16x8*)&pAl[16 * KP + off_];          \
        bh[buf][0] = *(const bf16x8*)&pBh[off_];                    \
        bh[buf][1] = *(const bf16x8*)&pBh[16 * KP + off_];          \
        bl[buf][0] = *(const bf16x8*)&pBl[off_];                    \
        bl[buf][1] = *(const bf16x8*)&pBl[16 * KP + off_];          \
    }

__global__ __launch_bounds__(1024)
void cbp_gram(const short* __restrict__ xh, const short* __restrict__ xl,
              const float* __restrict__ s1, const float* __restrict__ s2,
              const int*   __restrict__ h1, const int*   __restrict__ h2,
              float* __restrict__ partials) {
    __shared__ float sk[PROJ];                 // 32 KB private sketch

    const int tid = threadIdx.x;
    const int blk = blockIdx.x;
    const int xcd = blk & 7;
    const int sub = blk >> 3;                  // 0..31
    const int hi  = sub >> 4;
    const int q   = sub & 15;                  // quarter of the 8x8 tile grid
    const int b   = 2 * xcd + hi;

    for (int i = tid; i < PROJ; i += 1024) sk[i] = 0.f;
    __syncthreads();

    const int wave = tid >> 6, lane = tid & 63;
    const int quad = lane >> 4, l15 = lane & 15;
    const int tile = q * 4 + (wave >> 2);      // 0..63 in the 8x8 grid
    const int I = tile >> 3, J = tile & 7;
    const int qr = ((wave >> 1) & 1) * 32;     // 32x32 quadrant within tile
    const int qc = (wave & 1) * 32;
    const int c1 = I * 64 + qr;
    const int c2 = J * 64 + qc;

    const size_t rowA = ((size_t)b * NC + c1 + l15) * KP + quad * 8;
    const size_t rowB = ((size_t)b * NC + c2 + l15) * KP + quad * 8;
    const short* pAh = xh + rowA;  const short* pAl = xl + rowA;
    const short* pBh = xh + rowB;  const short* pBl = xl + rowB;

    f32x4 acc[2][2];
#pragma unroll
    for (int i = 0; i < 2; ++i)
#pragma unroll
        for (int j = 0; j < 2; ++j) acc[i][j] = (f32x4){0.f, 0.f, 0.f, 0.f};

    bf16x8 ah[2][2], al[2][2], bh[2][2], bl[2][2];   // [buf][i]
    LOADFRAGS(0, 0)
#pragma unroll
    for (int kc = 0; kc < 7; ++kc) {
        const int cur = kc & 1;
        if (kc < 6) LOADFRAGS(cur ^ 1, kc + 1)
#pragma unroll
        for (int i = 0; i < 2; ++i)
#pragma unroll
            for (int j = 0; j < 2; ++j) {
                acc[i][j] = __builtin_amdgcn_mfma_f32_16x16x32_bf16(ah[cur][i], bh[cur][j], acc[i][j], 0, 0, 0);
                acc[i][j] = __builtin_amdgcn_mfma_f32_16x16x32_bf16(ah[cur][i], bl[cur][j], acc[i][j], 0, 0, 0);
                acc[i][j] = __builtin_amdgcn_mfma_f32_16x16x32_bf16(al[cur][i], bh[cur][j], acc[i][j], 0, 0, 0);
            }
    }

    // Epilogue scatter. C/D layout: col = lane&15 (c2), row = quad*4+reg (c1).
    // h/s read from global (2-6 KB hot region, L2-broadcast).
    int   ha[2][4], hb[2];
    float sa[2][4], sb[2];
#pragma unroll
    for (int i = 0; i < 2; ++i) {
        const int r0 = c1 + i * 16 + quad * 4;
#pragma unroll
        for (int rg = 0; rg < 4; ++rg) {
            ha[i][rg] = h1[r0 + rg];
            sa[i][rg] = s1[r0 + rg];
        }
    }
#pragma unroll
    for (int j = 0; j < 2; ++j) {
        const int c = c2 + j * 16 + l15;
        hb[j] = h2[c];
        sb[j] = s2[c];
    }
#pragma unroll
    for (int i = 0; i < 2; ++i)
#pragma unroll
        for (int j = 0; j < 2; ++j)
#pragma unroll
            for (int rg = 0; rg < 4; ++rg) {
                const int bin = (ha[i][rg] + hb[j]) & (PROJ - 1);
                atomicAdd(&sk[bin], sa[i][rg] * sb[j] * acc[i][j][rg]);  // ds_add
            }
    __syncthreads();

    float4* dst = (float4*)(partials + (size_t)blk * PROJ);
    const float4* src = (const float4*)sk;
    for (int i = tid; i < PROJ / 4; i += 1024) dst[i] = src[i];
}

// ---------------------------------------------------------------------------
// Kernel 2 (reduce): sum 16 partials/bin + signed sqrt + per-block ssq.
// grid = 512; blk&7 matches gram's XCD pin so partials are read from local L2.
// Lane-coalesced: lane = bin, partial index rotated to spread HBM channels.
// ---------------------------------------------------------------------------
__global__ __launch_bounds__(256)
void cbp_reduce(const float* __restrict__ partials, float* __restrict__ y,
                float* __restrict__ ssqp) {
    const int blk = blockIdx.x;
    const int xcd = blk & 7;
    const int k   = blk >> 3;          // 0..63
    const int hi  = k >> 5;
    const int seg = k & 31;
    const int b   = 2 * xcd + hi;
    const int tid = threadIdx.x;
    const int bin = seg * 256 + tid;

    float s = 0.f;
#pragma unroll
    for (int u = 0; u < 16; ++u) {
        const int u2 = (u + seg) & 15;                 // rotate partial order
        const int pb = ((hi * 16 + u2) << 3) | xcd;    // gram's blk for (b,q=u2)
        s += partials[(size_t)pb * PROJ + bin];
    }

    const float m = sqrtf(fabsf(s) + 1e-8f);
    const float o = (s > 0.f) ? m : (s < 0.f ? -m : 0.f);   // sign(0)=0
    y[b * PROJ + bin] = o;

    __shared__ float red[256];
    red[tid] = o * o;
    __syncthreads();
#pragma unroll
    for (int st = 128; st >= 1; st >>= 1) {
        if (tid < st) red[tid] += red[tid + st];
        __syncthreads();
    }
    if (tid == 0) ssqp[blk] = red[0];
}

// ---------------------------------------------------------------------------
// Kernel 3 (norm): y_b /= max(||y_b||, 1e-12). grid = 32 (b, half-row).
// ---------------------------------------------------------------------------
__global__ __launch_bounds__(256)
void cbp_normalize(float* __restrict__ y, const float* __restrict__ ssqp) {
    const int b   = blockIdx.x >> 1;
    const int off = (blockIdx.x & 1) * 4096;
    const int tid = threadIdx.x;
    float ssq = 0.f;
#pragma unroll
    for (int seg = 0; seg < 32; ++seg)
        ssq += ssqp[(((b & 1) * 32 + seg) << 3) | (b >> 1)];
    const float inv = 1.0f / fmaxf(sqrtf(ssq), 1e-12f);

    float4* row = (float4*)&y[(size_t)b * PROJ + off];
#pragma unroll
    for (int j = 0; j < 4; ++j) {
        float4 v = row[j * 256 + tid];
        v.x *= inv; v.y *= inv; v.z *= inv; v.w *= inv;
        row[j * 256 + tid] = v;
    }
}

// ---------------------------------------------------------------------------
extern "C" void kernel_launch(void* const* d_in, const int* in_sizes, int n_in,
                              void* d_out, int out_size, void* d_ws, size_t ws_size,
                              hipStream_t stream) {
    const float* x  = (const float*)d_in[0];
    const float* s1 = (const float*)d_in[1];
    const float* s2 = (const float*)d_in[2];
    const int*   h1 = (const int*)d_in[3];
    const int*   h2 = (const int*)d_in[4];
    float* y = (float*)d_out;                    // [16, 8192]

    // ws layout (~15.8 MB used of 256 MiB):
    short* xh = (short*)d_ws;                    // 3.67 MB
    short* xl = xh + XELE;                       // 3.67 MB
    float* partials = (float*)(xl + XELE);       // 256 * 32 KB = 8.39 MB
    float* ssqp = partials + (size_t)256 * PROJ; // 512 floats

    hipLaunchKernelGGL(cbp_prep, dim3(1792), dim3(256), 0, stream, x, xh, xl);
    hipLaunchKernelGGL(cbp_gram, dim3(256), dim3(1024), 0, stream,
                       xh, xl, s1, s2, h1, h2, partials);
    hipLaunchKernelGGL(cbp_reduce, dim3(512), dim3(256), 0, stream,
                       partials, y, ssqp);
    hipLaunchKernelGGL(cbp_normalize, dim3(32), dim3(256), 0, stream, y, ssqp);
}

// Round 10
// 105.356 us; speedup vs baseline: 1.1399x; 1.0273x over previous
//
#include <hip/hip_runtime.h>
#include <math.h>

#define PROJ 8192
#define NB   16
#define NC   512
#define HW   196      // 14*14
#define KP   224      // K padded (7 chunks of 32)
#define LST  40       // LDS row stride in bf16 elems (80 B: 16B-aligned, <=2-way banks)
#define XELE ((size_t)NB * NC * KP)   // elems per bf16 array

typedef __attribute__((ext_vector_type(8))) short bf16x8;   // 16 B: MFMA A/B frag
typedef __attribute__((ext_vector_type(4))) short short4v;
typedef __attribute__((ext_vector_type(4))) float f32x4;    // MFMA C/D frag

__device__ __forceinline__ unsigned bf16_rne(float f) {
    unsigned u = __builtin_bit_cast(unsigned, f);
    return (u + 0x7fffu + ((u >> 16) & 1u)) >> 16;
}

// ---------------------------------------------------------------------------
// Kernel 0 (prep): x fp32 [8192 x 196] -> xh/xl bf16 [8192 x 224] (K padded).
// Split precision: x = hi + lo; G = hh + hl + lh (lo*lo dropped, ~2^-18).
// ---------------------------------------------------------------------------
__global__ __launch_bounds__(256)
void cbp_prep(const float* __restrict__ x,
              short* __restrict__ xh, short* __restrict__ xl) {
    const int id  = blockIdx.x * 256 + threadIdx.x;   // quad id over 8192*56
    const int q   = id % 56;
    const int row = id / 56;
    float4 v = {0.f, 0.f, 0.f, 0.f};
    if (q < 49) v = *(const float4*)&x[(size_t)row * HW + 4 * q];  // 196 = 49*4
    const float f[4] = {v.x, v.y, v.z, v.w};
    short4v h, l;
#pragma unroll
    for (int c = 0; c < 4; ++c) {
        const unsigned hb = bf16_rne(f[c]);
        h[c] = (short)hb;
        l[c] = (short)bf16_rne(f[c] - __builtin_bit_cast(float, hb << 16));
    }
    *(short4v*)&xh[(size_t)row * KP + 4 * q] = h;
    *(short4v*)&xl[(size_t)row * KP + 4 * q] = l;
}

// ---------------------------------------------------------------------------
// Kernel 1 (gram): 256 blocks x 512 threads, LDS 72KB -> 2 blocks/CU capable
// (dispatch imbalance absorbed concurrently; 16 waves/CU when doubled).
// Block = one 128x128 Gram tile of batch b. Staging is a PURE bf16 copy
// (prep did the convert): 4x 16B global loads -> 4x ds_write_b128 per thread
// per chunk, VGPR-prefetched one chunk ahead. 8 waves each own a 32x64
// sub-tile (acc 2x4). Scatter into private 32KB LDS sketch, dense dump.
// blk&7 pins an XCD to a batch pair: b = 2*(blk&7) + (blk>>7).
// ---------------------------------------------------------------------------
__global__ __launch_bounds__(512, 2)
void cbp_gram(const short* __restrict__ xh, const short* __restrict__ xl,
              const float* __restrict__ s1, const float* __restrict__ s2,
              const int*   __restrict__ h1, const int*   __restrict__ h2,
              float* __restrict__ partials) {
    __shared__ float sk[PROJ];          // 32 KB private sketch
    __shared__ short Ah[128 * LST];     // 10 KB each
    __shared__ short Al[128 * LST];
    __shared__ short Bh[128 * LST];
    __shared__ short Bl[128 * LST];
    __shared__ int   lh1[128], lh2[128];
    __shared__ float ls1[128], ls2[128];

    const int tid = threadIdx.x;
    const int blk = blockIdx.x;
    const int xcd = blk & 7;
    const int hi  = blk >> 7;
    const int b   = 2 * xcd + hi;
    const int tile = (blk >> 3) & 15;
    const int I = tile >> 2, J = tile & 3;
    const int c1base = I * 128, c2base = J * 128;

    for (int i = tid; i < PROJ; i += 512) sk[i] = 0.f;
    if (tid < 128) {
        lh1[tid] = h1[c1base + tid];  ls1[tid] = s1[c1base + tid];
    } else if (tid < 256) {
        const int t = tid - 128;
        lh2[t] = h2[c2base + t];  ls2[t] = s2[c2base + t];
    }

    const int wave = tid >> 6, lane = tid & 63;
    const int quad = lane >> 4, l15 = lane & 15;
    const int wr = (wave >> 1) * 32;    // 32x64 sub-tile per wave
    const int wc = (wave & 1) * 64;

    // Staging: thread -> (row sr, 16B slot sl) of the 64B row-chunk.
    const int sr = tid >> 2;            // 0..127
    const int sl = tid & 3;             // 0..3

    const size_t baseA = ((size_t)b * NC + c1base + sr) * KP + sl * 8;
    const size_t baseB = ((size_t)b * NC + c2base + sr) * KP + sl * 8;

    bf16x8 pAh, pAl, pBh, pBl;          // prefetch regs (chunk kc+1)
    pAh = *(const bf16x8*)&xh[baseA];
    pAl = *(const bf16x8*)&xl[baseA];
    pBh = *(const bf16x8*)&xh[baseB];
    pBl = *(const bf16x8*)&xl[baseB];

    f32x4 acc[2][4];
#pragma unroll
    for (int i = 0; i < 2; ++i)
#pragma unroll
        for (int j = 0; j < 4; ++j) acc[i][j] = (f32x4){0.f, 0.f, 0.f, 0.f};

    for (int kc = 0; kc < 7; ++kc) {
        __syncthreads();                // LDS consumed (covers h/s on kc==0)
        *(bf16x8*)&Ah[sr * LST + sl * 8] = pAh;
        *(bf16x8*)&Al[sr * LST + sl * 8] = pAl;
        *(bf16x8*)&Bh[sr * LST + sl * 8] = pBh;
        *(bf16x8*)&Bl[sr * LST + sl * 8] = pBl;
        if (kc < 6) {                   // prefetch next chunk
            const size_t off = (size_t)(kc + 1) * 32;
            pAh = *(const bf16x8*)&xh[baseA + off];
            pAl = *(const bf16x8*)&xl[baseA + off];
            pBh = *(const bf16x8*)&xh[baseB + off];
            pBl = *(const bf16x8*)&xl[baseB + off];
        }
        __syncthreads();

        bf16x8 ahf[2], alf[2], bhf[4], blf[4];
#pragma unroll
        for (int i = 0; i < 2; ++i) {
            const int ra = wr + i * 16 + l15;
            ahf[i] = *(const bf16x8*)&Ah[ra * LST + quad * 8];
            alf[i] = *(const bf16x8*)&Al[ra * LST + quad * 8];
        }
#pragma unroll
        for (int j = 0; j < 4; ++j) {
            const int rb = wc + j * 16 + l15;
            bhf[j] = *(const bf16x8*)&Bh[rb * LST + quad * 8];
            blf[j] = *(const bf16x8*)&Bl[rb * LST + quad * 8];
        }
#pragma unroll
        for (int i = 0; i < 2; ++i)
#pragma unroll
            for (int j = 0; j < 4; ++j) {
                acc[i][j] = __builtin_amdgcn_mfma_f32_16x16x32_bf16(ahf[i], bhf[j], acc[i][j], 0, 0, 0);
                acc[i][j] = __builtin_amdgcn_mfma_f32_16x16x32_bf16(ahf[i], blf[j], acc[i][j], 0, 0, 0);
                acc[i][j] = __builtin_amdgcn_mfma_f32_16x16x32_bf16(alf[i], bhf[j], acc[i][j], 0, 0, 0);
            }
    }

    // Scatter. C/D layout: col = lane&15 (c2), row = quad*4+reg (c1).
#pragma unroll
    for (int i = 0; i < 2; ++i) {
        const int r0 = wr + i * 16 + quad * 4;
#pragma unroll
        for (int j = 0; j < 4; ++j) {
            const int c = wc + j * 16 + l15;
            const int h2v = lh2[c];
            const float s2v = ls2[c];
#pragma unroll
            for (int rg = 0; rg < 4; ++rg) {
                const int r = r0 + rg;
                const int bin = (lh1[r] + h2v) & (PROJ - 1);
                atomicAdd(&sk[bin], ls1[r] * s2v * acc[i][j][rg]);  // ds_add
            }
        }
    }
    __syncthreads();

    float4* dst = (float4*)(partials + (size_t)blk * PROJ);
    const float4* src = (const float4*)sk;
    for (int i = tid; i < PROJ / 4; i += 512) dst[i] = src[i];
}

// ---------------------------------------------------------------------------
// Kernel 2 (reduce): sum 16 partials/bin + signed sqrt + per-block ssq.
// grid = 512; blk&7 = xcd matches gram's pin so partials read from local L2.
// ---------------------------------------------------------------------------
__global__ __launch_bounds__(256)
void cbp_reduce(const float* __restrict__ partials, float* __restrict__ y,
                float* __restrict__ ssqp) {
    const int blk = blockIdx.x;
    const int xcd = blk & 7;
    const int k   = blk >> 3;          // 0..63
    const int hi  = k >> 5;
    const int seg = k & 31;
    const int b   = 2 * xcd + hi;
    const int tid = threadIdx.x;
    const int bin = seg * 256 + tid;

    float s = 0.f;
#pragma unroll
    for (int u = 0; u < 16; ++u) {
        const int u2 = (u + seg) & 15;                  // rotate partial order
        const int pb = xcd | (u2 << 3) | (hi << 7);     // gram blk of (b,tile=u2)
        s += partials[(size_t)pb * PROJ + bin];
    }

    const float m = sqrtf(fabsf(s) + 1e-8f);
    const float o = (s > 0.f) ? m : (s < 0.f ? -m : 0.f);   // sign(0)=0
    y[b * PROJ + bin] = o;

    __shared__ float red[256];
    red[tid] = o * o;
    __syncthreads();
#pragma unroll
    for (int st = 128; st >= 1; st >>= 1) {
        if (tid < st) red[tid] += red[tid + st];
        __syncthreads();
    }
    if (tid == 0) ssqp[blk] = red[0];
}

// ---------------------------------------------------------------------------
// Kernel 3 (norm): y_b /= max(||y_b||, 1e-12). grid = 32 (b, half-row).
// ---------------------------------------------------------------------------
__global__ __launch_bounds__(256)
void cbp_normalize(float* __restrict__ y, const float* __restrict__ ssqp) {
    const int b   = blockIdx.x >> 1;
    const int off = (blockIdx.x & 1) * 4096;
    const int tid = threadIdx.x;
    float ssq = 0.f;
#pragma unroll
    for (int seg = 0; seg < 32; ++seg)
        ssq += ssqp[(((b & 1) * 32 + seg) << 3) | (b >> 1)];
    const float inv = 1.0f / fmaxf(sqrtf(ssq), 1e-12f);

    float4* row = (float4*)&y[(size_t)b * PROJ + off];
#pragma unroll
    for (int j = 0; j < 4; ++j) {
        float4 v = row[j * 256 + tid];
        v.x *= inv; v.y *= inv; v.z *= inv; v.w *= inv;
        row[j * 256 + tid] = v;
    }
}

// ---------------------------------------------------------------------------
extern "C" void kernel_launch(void* const* d_in, const int* in_sizes, int n_in,
                              void* d_out, int out_size, void* d_ws, size_t ws_size,
                              hipStream_t stream) {
    const float* x  = (const float*)d_in[0];
    const float* s1 = (const float*)d_in[1];
    const float* s2 = (const float*)d_in[2];
    const int*   h1 = (const int*)d_in[3];
    const int*   h2 = (const int*)d_in[4];
    float* y = (float*)d_out;                    // [16, 8192]

    // ws layout (~15.8 MB used):
    short* xh = (short*)d_ws;                    // 3.67 MB
    short* xl = xh + XELE;                       // 3.67 MB
    float* partials = (float*)(xl + XELE);       // 256 * 32 KB = 8.39 MB
    float* ssqp = partials + (size_t)256 * PROJ; // 512 floats

    hipLaunchKernelGGL(cbp_prep, dim3(1792), dim3(256), 0, stream, x, xh, xl);
    hipLaunchKernelGGL(cbp_gram, dim3(256), dim3(512), 0, stream,
                       xh, xl, s1, s2, h1, h2, partials);
    hipLaunchKernelGGL(cbp_reduce, dim3(512), dim3(256), 0, stream,
                       partials, y, ssqp);
    hipLaunchKernelGGL(cbp_normalize, dim3(32), dim3(256), 0, stream, y, ssqp);
}